// Round 9
// baseline (97.362 us; speedup 1.0000x reference)
//
#include <hip/hip_runtime.h>
#include <math.h>

#define BB 4
#define NN 4096
#define DD 128
#define HS 16            // n slices per batch (256 n each)
#define NIT 4            // 64-n tiles per slice
#define QG 32            // m quad-groups per batch (128 m each; 4 waves x 32)
#define NPS 128          // psum partials per (b,n): q*4+w

typedef __attribute__((ext_vector_type(8))) short bf16x8;
typedef __attribute__((ext_vector_type(4))) float f32x4;
typedef __attribute__((ext_vector_type(4))) unsigned short u16x4;

__device__ __forceinline__ void mfma_16x16x32_bf16(f32x4& d, bf16x8 a, bf16x8 b) {
  asm volatile("v_mfma_f32_16x16x32_bf16 %0, %1, %2, %0" : "+v"(d) : "v"(a), "v"(b));
}

__device__ __forceinline__ void gload16(const void* g, void* lds) {
  __builtin_amdgcn_global_load_lds(
      (const __attribute__((address_space(1))) void*)g,
      (__attribute__((address_space(3))) void*)lds, 16, 0, 0);
}

__device__ __forceinline__ float vexp2(float x) {  // raw v_exp_f32 = 2^x
  float r; asm("v_exp_f32 %0, %1" : "=v"(r) : "v"(x)); return r;
}

__device__ __forceinline__ unsigned short f2b(float x) {  // RNE f32->bf16
  union { float f; unsigned u; } v; v.f = x;
  unsigned r = v.u + 0x7fffu + ((v.u >> 16) & 1u);
  return (unsigned short)(r >> 16);
}

// ---- kernel 1: cast to bf16 (ft pre-scaled by 0.1*log2e) + fs inv-norms ----
// thread handles 4 consecutive floats of fs AND of ft; 32 threads per row.
__global__ __launch_bounds__(256) void k_prep(const float* __restrict__ fs,
                                              const float* __restrict__ ft,
                                              unsigned short* __restrict__ fsb,
                                              unsigned short* __restrict__ ftb,
                                              float* __restrict__ inv_norm) {
  int i = blockIdx.x * 256 + threadIdx.x;    // float4 index
  float4 a = ((const float4*)fs)[i];
  float4 c = ((const float4*)ft)[i];
  u16x4 oa; oa[0] = f2b(a.x); oa[1] = f2b(a.y); oa[2] = f2b(a.z); oa[3] = f2b(a.w);
  ((u16x4*)fsb)[i] = oa;
  const float C = 0.14426950408889634f;      // 0.1*log2(e): 2^acc == exp(dot/10)
  u16x4 oc; oc[0] = f2b(c.x * C); oc[1] = f2b(c.y * C);
  oc[2] = f2b(c.z * C); oc[3] = f2b(c.w * C);
  ((u16x4*)ftb)[i] = oc;
  float s = a.x * a.x + a.y * a.y + a.z * a.z + a.w * a.w;
#pragma unroll
  for (int off = 1; off <= 16; off <<= 1) s += __shfl_xor(s, off);
  if ((threadIdx.x & 31) == 0) inv_norm[i >> 5] = 1.0f / sqrtf(s);
}

// ---- kernel 2: LDS-staged transposed GEMM C[m][n] + fused epilogue ---------
// Block (b, h, q): 4 waves own 128 m-rows of ft (A-frags in regs), stream the
// shared fs slice (256 n) in 4 tiles of 64 via global_load_lds double-buffer,
// ONE barrier per tile. Rolled it-loop (full unroll spilled: round 7).
// psum partials per wave straight to global ([b][n][q*4+w], no LDS scratch);
// argmax in-register via packed keys (quantized value | 4-bit inverse code).
__global__ __launch_bounds__(256, 5) void k_main(const unsigned short* __restrict__ fsb,
                                                 const unsigned short* __restrict__ ftb,
                                                 const float* __restrict__ inv_norm,
                                                 float* __restrict__ psum,
                                                 float2* __restrict__ pmax) {
  __shared__ __align__(16) char smem[32768];   // 2 x 16KB fs tile dbuf

  const int t = threadIdx.x;
  const int w = t >> 6, lane = t & 63;
  const int l15 = lane & 15, g = lane >> 4;
  const int bid = blockIdx.x;
  const int q = bid & 31, h = (bid >> 5) & 15, b = bid >> 9;
  const int m0 = q * 128 + w * 32;

  // staging address (16KB tile = 64 rows x 256B, involution swizzle on 16B col)
  const int srcThr = ((t >> 4) << 8) + (((t & 15) ^ ((t >> 4) & 15)) << 4);
  const int ldsThr = w * 1024;                 // wave-uniform base (+lane*16 by HW)

  // A fragments: ft rows m0..m0+31 (pre-scaled), straight from global, once
  const unsigned short* Ab = ftb + ((size_t)b * NN + m0) * DD;
  bf16x8 af[4][2];
#pragma unroll
  for (int kk = 0; kk < 4; kk++)
#pragma unroll
    for (int mf = 0; mf < 2; mf++)
      af[kk][mf] = *(const bf16x8*)(Ab + (mf * 16 + l15) * DD + kk * 32 + g * 8);

  const char* gB0 = (const char*)(fsb + ((size_t)b * NN + h * 256) * DD);
  const float* invb = inv_norm + (size_t)b * NN + h * 256;

  // all n-scales for this slice, hoisted (16 VGPR)
  float svn[NIT][4];
#pragma unroll
  for (int it = 0; it < NIT; it++)
#pragma unroll
    for (int fj = 0; fj < 4; fj++) svn[it][fj] = invb[it * 64 + fj * 16 + l15];

  char* cb = smem;            // compute buffer
  char* nb = smem + 16384;    // prefetch buffer

  // stage tile 0
#pragma unroll
  for (int p = 0; p < 4; p++)
    gload16(gB0 + p * 4096 + srcThr, cb + p * 4096 + ldsThr);

  float bkey[2][4];
#pragma unroll
  for (int mf = 0; mf < 2; mf++)
#pragma unroll
    for (int j = 0; j < 4; j++) bkey[mf][j] = 0.0f;

  float* psumB = psum + (size_t)b * NN * NPS + (size_t)h * 256 * NPS + q * 4 + w;

#pragma unroll 1
  for (int it = 0; it < NIT; ++it) {
    __syncthreads();          // tile it staged & visible; prev buffer free
    if (it + 1 < NIT) {       // prefetch tile it+1 (in flight across compute)
      const char* gBn = gB0 + (it + 1) * 16384;
#pragma unroll
      for (int p = 0; p < 4; p++)
        gload16(gBn + p * 4096 + srcThr, nb + p * 4096 + ldsThr);
    }
    // MFMA: 32 m x 64 n, K=128
    f32x4 acc[2][4] = {};
#pragma unroll
    for (int kk = 0; kk < 4; kk++) {
      bf16x8 bf[4];
#pragma unroll
      for (int fj = 0; fj < 4; fj++)
        bf[fj] = *(const bf16x8*)(cb + (fj * 16 + l15) * 256 + (((kk * 4 + g) ^ l15) << 4));
#pragma unroll
      for (int mf = 0; mf < 2; mf++)
#pragma unroll
        for (int fj = 0; fj < 4; fj++)
          mfma_16x16x32_bf16(acc[mf][fj], af[kk][mf], bf[fj]);
    }
    // exp col-sums over this wave's 32 m (acc = dot*0.1*log2e -> 2^acc)
#pragma unroll
    for (int fj = 0; fj < 4; fj++) {
      float e0 = vexp2(acc[0][fj][0]), e1 = vexp2(acc[0][fj][1]);
      float e2 = vexp2(acc[0][fj][2]), e3 = vexp2(acc[0][fj][3]);
      float e4 = vexp2(acc[1][fj][0]), e5 = vexp2(acc[1][fj][1]);
      float e6 = vexp2(acc[1][fj][2]), e7 = vexp2(acc[1][fj][3]);
      float s = ((e0 + e1) + (e2 + e3)) + ((e4 + e5) + (e6 + e7));
      s += __shfl_xor(s, 16);
      s += __shfl_xor(s, 32);
      if (g == 0) psumB[(it * 64 + fj * 16 + l15) * NPS] = s;
    }
    // packed-key running argmax over n (3 VALU/elem: fma, and|or, max)
    const unsigned codebase = (unsigned)((3 - it) << 2);
#pragma unroll
    for (int fj = 0; fj < 4; fj++) {
      const unsigned code = codebase | (unsigned)(3 - fj);   // bigger = earlier n
#pragma unroll
      for (int mf = 0; mf < 2; mf++)
#pragma unroll
        for (int j = 0; j < 4; j++) {
          float v = fmaf(acc[mf][fj][j], svn[it][fj], 4.0f); // positive -> uint order
          unsigned kb = (__float_as_uint(v) & 0xFFFFFFF0u) | code;
          bkey[mf][j] = fmaxf(bkey[mf][j], __uint_as_float(kb));
        }
    }
    char* tmp = cb; cb = nb; nb = tmp;
  }

  // pmax finalize: exact cross-l15 argmax, once
#pragma unroll
  for (int mf = 0; mf < 2; mf++)
#pragma unroll
    for (int j = 0; j < 4; j++) {
      unsigned bits = __float_as_uint(bkey[mf][j]);
      unsigned code = bits & 15u;
      int itw = 3 - (int)(code >> 2);
      int fjw = 3 - (int)(code & 3u);
      int n = h * 256 + itw * 64 + fjw * 16 + l15;
      float vq = __uint_as_float(bits & 0xFFFFFFF0u);
#pragma unroll
      for (int off = 1; off <= 8; off <<= 1) {
        float ov = __shfl_xor(vq, off);
        int   on = __shfl_xor(n, off);
        if (ov > vq || (ov == vq && on < n)) { vq = ov; n = on; }
      }
      if (l15 == 0) {
        int m = m0 + mf * 16 + g * 4 + j;
        float2 pr; pr.x = vq; pr.y = __int_as_float(n);
        pmax[((size_t)b * NN + m) * HS + h] = pr;
      }
    }
}

// ---- kernel 3: per-row finish: argmax over 16 slices, sum 128 psum, pos dot
__global__ __launch_bounds__(256) void k_post(const float* __restrict__ fs,
                                              const float* __restrict__ ft,
                                              const float* __restrict__ psum,
                                              const float2* __restrict__ pmax,
                                              float* __restrict__ blockpart) {
  __shared__ float part[4];
  int w = threadIdx.x >> 6, lane = threadIdx.x & 63;
  int row = blockIdx.x * 4 + w;          // flat b*N + p
  int b = row >> 12;
  // argmax over the 16 h-slices
  float v = -INFINITY; int i = 0x7fffffff;
  if (lane < HS) {
    float2 pm = pmax[(size_t)row * HS + lane];
    v = pm.x; i = __float_as_int(pm.y);
  }
#pragma unroll
  for (int off = 1; off <= 8; off <<= 1) {
    float ov = __shfl_xor(v, off);
    int   oi = __shfl_xor(i, off);
    if (ov > v || (ov == v && oi < i)) { v = ov; i = oi; }
  }
  int j = __shfl(i, 0);
  // sum the 128 contiguous psum partials of all_exp
  float2 qv = ((const float2*)(psum + (size_t)row * NPS))[lane];
  float tot = qv.x + qv.y;
#pragma unroll
  for (int off = 1; off <= 32; off <<= 1) tot += __shfl_xor(tot, off);
  // fp32 dot of fs[row] with ft[b, j]
  float2 a = ((const float2*)(fs + (size_t)row * DD))[lane];
  float2 c = ((const float2*)(ft + ((size_t)b * NN + j) * DD))[lane];
  float s = a.x * c.x + a.y * c.y;
#pragma unroll
  for (int off = 32; off > 0; off >>= 1) s += __shfl_xor(s, off);
  if (lane == 0) {
    float term = logf(tot) - s * 0.1f;
    part[w] = fminf(term, 92.103403719761827f);   // ratio clip at 1e-40
  }
  __syncthreads();
  if (threadIdx.x == 0)
    blockpart[blockIdx.x] = part[0] + part[1] + part[2] + part[3];
}

// ---- kernel 4: final deterministic reduction ------------------------------
__global__ __launch_bounds__(256) void k_final(const float* __restrict__ blockpart,
                                               float* __restrict__ out) {
  __shared__ float red[256];
  float s = 0.0f;
  for (int i = threadIdx.x; i < (BB * NN) / 4; i += 256) s += blockpart[i];
  red[threadIdx.x] = s;
  __syncthreads();
  for (int st = 128; st > 0; st >>= 1) {
    if (threadIdx.x < st) red[threadIdx.x] += red[threadIdx.x + st];
    __syncthreads();
  }
  if (threadIdx.x == 0) out[0] = red[0] * (1.0f / (BB * NN));
}

extern "C" void kernel_launch(void* const* d_in, const int* in_sizes, int n_in,
                              void* d_out, int out_size, void* d_ws, size_t ws_size,
                              hipStream_t stream) {
  const float* fs = (const float*)d_in[0];
  const float* ft = (const float*)d_in[1];
  float* out = (float*)d_out;

  const size_t NE = (size_t)BB * NN * DD;
  unsigned short* fsb = (unsigned short*)d_ws;                   // 4MB
  unsigned short* ftb = fsb + NE;                                // 4MB
  float*  inv_norm = (float*)(ftb + NE);                         // 64KB
  float*  psum     = inv_norm + (size_t)BB * NN;                 // B*N*128 f32 (8MB)
  float2* pmax     = (float2*)(psum + (size_t)BB * NN * NPS);    // B*N*16 f32x2 (2MB)
  float*  blockpart = (float*)(pmax + (size_t)BB * NN * HS);     // B*N/4 f32

  // k_prep: one thread per 4 floats of each input -> NE/4/256 = 2048 blocks
  k_prep<<<(int)(NE / 4 / 256), 256, 0, stream>>>(fs, ft, fsb, ftb, inv_norm);
  // k_main: b(4) x h(16) x q(32) = 2048 blocks
  k_main<<<BB * HS * QG, 256, 0, stream>>>(fsb, ftb, inv_norm, psum, pmax);
  k_post<<<(BB * NN) / 4, 256, 0, stream>>>(fs, ft, psum, pmax, blockpart);
  k_final<<<1, 256, 0, stream>>>(blockpart, out);
}

// Round 10
// 64.772 us; speedup vs baseline: 1.5032x; 1.5032x over previous
//
#include <hip/hip_runtime.h>
#include <math.h>

#define BB 4
#define NN 4096
#define DD 128
#define HS 16            // n slices per batch (256 n each)
#define NIT 8            // 32-n tiles per slice
#define QG 32            // m quad-groups per batch (128 m each; 4 waves x 32)

typedef __attribute__((ext_vector_type(8))) short bf16x8;
typedef __attribute__((ext_vector_type(4))) float f32x4;
typedef __attribute__((ext_vector_type(4))) unsigned short u16x4;

__device__ __forceinline__ void mfma_16x16x32_bf16(f32x4& d, bf16x8 a, bf16x8 b) {
  asm volatile("v_mfma_f32_16x16x32_bf16 %0, %1, %2, %0" : "+v"(d) : "v"(a), "v"(b));
}

__device__ __forceinline__ void gload16(const void* g, void* lds) {
  __builtin_amdgcn_global_load_lds(
      (const __attribute__((address_space(1))) void*)g,
      (__attribute__((address_space(3))) void*)lds, 16, 0, 0);
}

__device__ __forceinline__ float vexp2(float x) {  // raw v_exp_f32 = 2^x
  float r; asm("v_exp_f32 %0, %1" : "=v"(r) : "v"(x)); return r;
}

__device__ __forceinline__ unsigned short f2b(float x) {  // RNE f32->bf16
  union { float f; unsigned u; } v; v.f = x;
  unsigned r = v.u + 0x7fffu + ((v.u >> 16) & 1u);
  return (unsigned short)(r >> 16);
}

// ---- kernel 1: cast to bf16 (ft pre-scaled by 0.1*log2e) + fs inv-norms ----
__global__ __launch_bounds__(256) void k_prep(const float* __restrict__ fs,
                                              const float* __restrict__ ft,
                                              unsigned short* __restrict__ fsb,
                                              unsigned short* __restrict__ ftb,
                                              float* __restrict__ inv_norm) {
  int i = blockIdx.x * 256 + threadIdx.x;    // float4 index
  float4 a = ((const float4*)fs)[i];
  float4 c = ((const float4*)ft)[i];
  u16x4 oa; oa[0] = f2b(a.x); oa[1] = f2b(a.y); oa[2] = f2b(a.z); oa[3] = f2b(a.w);
  ((u16x4*)fsb)[i] = oa;
  const float C = 0.14426950408889634f;      // 0.1*log2(e): 2^acc == exp(dot/10)
  u16x4 oc; oc[0] = f2b(c.x * C); oc[1] = f2b(c.y * C);
  oc[2] = f2b(c.z * C); oc[3] = f2b(c.w * C);
  ((u16x4*)ftb)[i] = oc;
  float s = a.x * a.x + a.y * a.y + a.z * a.z + a.w * a.w;
#pragma unroll
  for (int off = 1; off <= 16; off <<= 1) s += __shfl_xor(s, off);
  if ((threadIdx.x & 31) == 0) inv_norm[i >> 5] = 1.0f / sqrtf(s);
}

// ---- kernel 2: LDS-staged transposed GEMM C[m][n] + fused epilogue ---------
// Block (b, h, q): 4 waves own 128 m-rows of ft (A-frags in regs), stream the
// shared 256-n fs slice in 8 tiles of 32 n via global_load_lds double-buffer,
// ONE barrier per tile. 20KB LDS -> 8 blocks/CU by LDS; launch_bounds(,6).
// Rolled it-loop (full unroll spilled: round 7). exp partials -> psb LDS
// scratch, coalesced write-out at the end (round 9's [b][n][128] scatter
// amplified writes 5x: 100MB). Argmax in-register via packed keys.
__global__ __launch_bounds__(256, 6) void k_main(const unsigned short* __restrict__ fsb,
                                                 const unsigned short* __restrict__ ftb,
                                                 const float* __restrict__ inv_norm,
                                                 float* __restrict__ psum,
                                                 float2* __restrict__ pmax) {
  __shared__ __align__(16) char smem[20480];   // 2x8KB fs dbuf + 4KB psb
  float* psb = (float*)(smem + 16384);         // [4 waves][256 n]

  const int t = threadIdx.x;
  const int w = t >> 6, lane = t & 63;
  const int l15 = lane & 15, g = lane >> 4;
  const int bid = blockIdx.x;
  const int q = bid & 31, h = (bid >> 5) & 15, b = bid >> 9;
  const int m0 = q * 128 + w * 32;

  // staging: 8KB tile = 32 n-rows x 256B K; 2 segs/thread, involution swizzle
  const int r0 = t >> 4, cp0 = t & 15;         // seg p*256+t: row = seg>>4
  const int src0 = r0 * 256 + ((cp0 ^ (r0 & 15)) << 4);          // p=0: rows 0..15
  const int src1 = (16 + r0) * 256 + ((cp0 ^ ((16 + r0) & 15)) << 4); // p=1: 16..31
  const int lds0 = w * 1024, lds1 = 4096 + w * 1024;   // wave-uniform bases

  // A fragments: ft rows m0..m0+31 (pre-scaled), straight from global, once
  const unsigned short* Ab = ftb + ((size_t)b * NN + m0) * DD;
  bf16x8 af[4][2];
#pragma unroll
  for (int kk = 0; kk < 4; kk++)
#pragma unroll
    for (int mf = 0; mf < 2; mf++)
      af[kk][mf] = *(const bf16x8*)(Ab + (mf * 16 + l15) * DD + kk * 32 + g * 8);

  const char* gB0 = (const char*)(fsb + ((size_t)b * NN + h * 256) * DD);
  const float* invb = inv_norm + (size_t)b * NN + h * 256;

  char* cb = smem;            // compute buffer
  char* nb = smem + 8192;     // prefetch buffer

  // stage tile 0
  gload16(gB0 + src0, cb + lds0);
  gload16(gB0 + src1, cb + lds1);

  float bkey[2][4];
#pragma unroll
  for (int mf = 0; mf < 2; mf++)
#pragma unroll
    for (int j = 0; j < 4; j++) bkey[mf][j] = 0.0f;

#pragma unroll 1
  for (int it = 0; it < NIT; ++it) {
    __syncthreads();          // tile it staged & visible; prev buffer free
    if (it + 1 < NIT) {       // prefetch tile it+1 (in flight across compute)
      const char* gBn = gB0 + (it + 1) * 8192;
      gload16(gBn + src0, nb + lds0);
      gload16(gBn + src1, nb + lds1);
    }
    // per-tile n-scales (2 scalars)
    float svn[2];
#pragma unroll
    for (int fj = 0; fj < 2; fj++) svn[fj] = invb[it * 32 + fj * 16 + l15];

    // MFMA: 32 m x 32 n, K=128
    f32x4 acc[2][2] = {};
#pragma unroll
    for (int kk = 0; kk < 4; kk++) {
      bf16x8 bf[2];
#pragma unroll
      for (int fj = 0; fj < 2; fj++)
        bf[fj] = *(const bf16x8*)(cb + (fj * 16 + l15) * 256 + (((kk * 4 + g) ^ l15) << 4));
#pragma unroll
      for (int mf = 0; mf < 2; mf++)
#pragma unroll
        for (int fj = 0; fj < 2; fj++)
          mfma_16x16x32_bf16(acc[mf][fj], af[kk][mf], bf[fj]);
    }
    // exp col-sums over this wave's 32 m (acc = dot*0.1*log2e -> 2^acc)
#pragma unroll
    for (int fj = 0; fj < 2; fj++) {
      float e0 = vexp2(acc[0][fj][0]), e1 = vexp2(acc[0][fj][1]);
      float e2 = vexp2(acc[0][fj][2]), e3 = vexp2(acc[0][fj][3]);
      float e4 = vexp2(acc[1][fj][0]), e5 = vexp2(acc[1][fj][1]);
      float e6 = vexp2(acc[1][fj][2]), e7 = vexp2(acc[1][fj][3]);
      float s = ((e0 + e1) + (e2 + e3)) + ((e4 + e5) + (e6 + e7));
      s += __shfl_xor(s, 16);
      s += __shfl_xor(s, 32);
      if (g == 0) psb[w * 256 + it * 32 + fj * 16 + l15] = s;
    }
    // packed-key running argmax over n (fma, and_or, max per elem)
    const unsigned codebase = (unsigned)((7 - it) << 1);
#pragma unroll
    for (int fj = 0; fj < 2; fj++) {
      const unsigned code = codebase | (unsigned)(1 - fj);   // bigger = earlier n
#pragma unroll
      for (int mf = 0; mf < 2; mf++)
#pragma unroll
        for (int j = 0; j < 4; j++) {
          float v = fmaf(acc[mf][fj][j], svn[fj], 4.0f);     // positive -> uint order
          unsigned kb = (__float_as_uint(v) & 0xFFFFFFF0u) | code;
          bkey[mf][j] = fmaxf(bkey[mf][j], __uint_as_float(kb));
        }
    }
    char* tmp = cb; cb = nb; nb = tmp;
  }
  __syncthreads();   // psb complete block-wide

  // psum write-out: combine 4 waves, coalesced (layout psum[b][q][n])
  {
    float s4 = (psb[t] + psb[256 + t]) + (psb[512 + t] + psb[768 + t]);
    psum[((size_t)(b * QG + q)) * NN + h * 256 + t] = s4;
  }

  // pmax finalize: exact cross-l15 argmax, once
#pragma unroll
  for (int mf = 0; mf < 2; mf++)
#pragma unroll
    for (int j = 0; j < 4; j++) {
      unsigned bits = __float_as_uint(bkey[mf][j]);
      unsigned code = bits & 15u;
      int itw = 7 - (int)(code >> 1);
      int fjw = 1 - (int)(code & 1u);
      int n = h * 256 + itw * 32 + fjw * 16 + l15;
      float vq = __uint_as_float(bits & 0xFFFFFFF0u);
#pragma unroll
      for (int off = 1; off <= 8; off <<= 1) {
        float ov = __shfl_xor(vq, off);
        int   on = __shfl_xor(n, off);
        if (ov > vq || (ov == vq && on < n)) { vq = ov; n = on; }
      }
      if (l15 == 0) {
        int m = m0 + mf * 16 + g * 4 + j;
        float2 pr; pr.x = vq; pr.y = __int_as_float(n);
        pmax[((size_t)b * NN + m) * HS + h] = pr;
      }
    }
}

// ---- kernel 3: per-row finish: argmax over 16 slices, sum 32 psum, pos dot -
__global__ __launch_bounds__(256) void k_post(const float* __restrict__ fs,
                                              const float* __restrict__ ft,
                                              const float* __restrict__ psum,
                                              const float2* __restrict__ pmax,
                                              float* __restrict__ blockpart) {
  __shared__ float part[4];
  int w = threadIdx.x >> 6, lane = threadIdx.x & 63;
  int row = blockIdx.x * 4 + w;          // flat b*N + p
  int b = row >> 12, pn = row & (NN - 1);
  // argmax over the 16 h-slices
  float v = -INFINITY; int i = 0x7fffffff;
  if (lane < HS) {
    float2 pm = pmax[(size_t)row * HS + lane];
    v = pm.x; i = __float_as_int(pm.y);
  }
#pragma unroll
  for (int off = 1; off <= 8; off <<= 1) {
    float ov = __shfl_xor(v, off);
    int   oi = __shfl_xor(i, off);
    if (ov > v || (ov == v && oi < i)) { v = ov; i = oi; }
  }
  int j = __shfl(i, 0);
  // sum the 32 q-partials of all_exp
  float tot = (lane < QG) ? psum[((size_t)(b * QG + lane)) * NN + pn] : 0.0f;
#pragma unroll
  for (int off = 1; off <= 16; off <<= 1) tot += __shfl_xor(tot, off);
  // fp32 dot of fs[row] with ft[b, j]
  float2 a = ((const float2*)(fs + (size_t)row * DD))[lane];
  float2 c = ((const float2*)(ft + ((size_t)b * NN + j) * DD))[lane];
  float s = a.x * c.x + a.y * c.y;
#pragma unroll
  for (int off = 32; off > 0; off >>= 1) s += __shfl_xor(s, off);
  if (lane == 0) {
    float term = logf(tot) - s * 0.1f;
    part[w] = fminf(term, 92.103403719761827f);   // ratio clip at 1e-40
  }
  __syncthreads();
  if (threadIdx.x == 0)
    blockpart[blockIdx.x] = part[0] + part[1] + part[2] + part[3];
}

// ---- kernel 4: final deterministic reduction ------------------------------
__global__ __launch_bounds__(256) void k_final(const float* __restrict__ blockpart,
                                               float* __restrict__ out) {
  __shared__ float red[256];
  float s = 0.0f;
  for (int i = threadIdx.x; i < (BB * NN) / 4; i += 256) s += blockpart[i];
  red[threadIdx.x] = s;
  __syncthreads();
  for (int st = 128; st > 0; st >>= 1) {
    if (threadIdx.x < st) red[threadIdx.x] += red[threadIdx.x + st];
    __syncthreads();
  }
  if (threadIdx.x == 0) out[0] = red[0] * (1.0f / (BB * NN));
}

extern "C" void kernel_launch(void* const* d_in, const int* in_sizes, int n_in,
                              void* d_out, int out_size, void* d_ws, size_t ws_size,
                              hipStream_t stream) {
  const float* fs = (const float*)d_in[0];
  const float* ft = (const float*)d_in[1];
  float* out = (float*)d_out;

  const size_t NE = (size_t)BB * NN * DD;
  unsigned short* fsb = (unsigned short*)d_ws;                   // 4MB
  unsigned short* ftb = fsb + NE;                                // 4MB
  float*  inv_norm = (float*)(ftb + NE);                         // 64KB
  float*  psum     = inv_norm + (size_t)BB * NN;                 // B*32*N f32 (2MB)
  float2* pmax     = (float2*)(psum + (size_t)BB * QG * NN);     // B*N*16 f32x2 (2MB)
  float*  blockpart = (float*)(pmax + (size_t)BB * NN * HS);     // B*N/4 f32

  k_prep<<<(int)(NE / 4 / 256), 256, 0, stream>>>(fs, ft, fsb, ftb, inv_norm);
  // k_main: b(4) x h(16) x q(32) = 2048 blocks
  k_main<<<BB * HS * QG, 256, 0, stream>>>(fsb, ftb, inv_norm, psum, pmax);
  k_post<<<(BB * NN) / 4, 256, 0, stream>>>(fs, ft, psum, pmax, blockpart);
  k_final<<<1, 256, 0, stream>>>(blockpart, out);
}

// Round 11
// 55.909 us; speedup vs baseline: 1.7414x; 1.1585x over previous
//
#include <hip/hip_runtime.h>
#include <math.h>

#define BB 4
#define NN 4096
#define DD 128
#define HS 16            // n slices per batch (256 n each)
#define NIT 8            // 32-n tiles per slice
#define QG 32            // m quad-groups per batch (128 m each; 4 waves x 32)

typedef __attribute__((ext_vector_type(8))) short bf16x8;
typedef __attribute__((ext_vector_type(4))) float f32x4;
typedef __attribute__((ext_vector_type(4))) unsigned short u16x4;

__device__ __forceinline__ void mfma_16x16x32_bf16(f32x4& d, bf16x8 a, bf16x8 b) {
  asm volatile("v_mfma_f32_16x16x32_bf16 %0, %1, %2, %0" : "+v"(d) : "v"(a), "v"(b));
}

__device__ __forceinline__ void gload16(const void* g, void* lds) {
  __builtin_amdgcn_global_load_lds(
      (const __attribute__((address_space(1))) void*)g,
      (__attribute__((address_space(3))) void*)lds, 16, 0, 0);
}

__device__ __forceinline__ float vexp2(float x) {  // raw v_exp_f32 = 2^x
  float r; asm("v_exp_f32 %0, %1" : "=v"(r) : "v"(x)); return r;
}

__device__ __forceinline__ unsigned short f2b(float x) {  // RNE f32->bf16
  union { float f; unsigned u; } v; v.f = x;
  unsigned r = v.u + 0x7fffu + ((v.u >> 16) & 1u);
  return (unsigned short)(r >> 16);
}

// ---- kernel 1: cast to bf16 (ft pre-scaled by 0.1*log2e) + fs inv-norms ----
__global__ __launch_bounds__(256) void k_prep(const float* __restrict__ fs,
                                              const float* __restrict__ ft,
                                              unsigned short* __restrict__ fsb,
                                              unsigned short* __restrict__ ftb,
                                              float* __restrict__ inv_norm) {
  int i = blockIdx.x * 256 + threadIdx.x;    // float4 index
  float4 a = ((const float4*)fs)[i];
  float4 c = ((const float4*)ft)[i];
  u16x4 oa; oa[0] = f2b(a.x); oa[1] = f2b(a.y); oa[2] = f2b(a.z); oa[3] = f2b(a.w);
  ((u16x4*)fsb)[i] = oa;
  const float C = 0.14426950408889634f;      // 0.1*log2(e): 2^acc == exp(dot/10)
  u16x4 oc; oc[0] = f2b(c.x * C); oc[1] = f2b(c.y * C);
  oc[2] = f2b(c.z * C); oc[3] = f2b(c.w * C);
  ((u16x4*)ftb)[i] = oc;
  float s = a.x * a.x + a.y * a.y + a.z * a.z + a.w * a.w;
#pragma unroll
  for (int off = 1; off <= 16; off <<= 1) s += __shfl_xor(s, off);
  if ((threadIdx.x & 31) == 0) inv_norm[i >> 5] = 1.0f / sqrtf(s);
}

// ---- kernel 2: ring-3 counted-vmcnt GEMM C[m][n] + fused epilogue ----------
// Block (b, h, q): 4 waves own 128 m-rows of ft (A-frags in regs), stream the
// shared 256-n fs slice in 8 tiles of 32 n staged 2-AHEAD into a 3-buffer LDS
// ring. Loop phase: s_waitcnt vmcnt(2) (tile it's loads done, tile it+1's
// stay in flight - NEVER drain to 0 mid-loop) -> raw s_barrier -> issue tile
// it+2 -> compute. No compiler VMEM inside the loop (inv_norm comes from an
// LDS table) so no stray compiler vmcnt(0). Rolled it-loop (r7: unroll spills).
__global__ __launch_bounds__(256, 5) void k_main(const unsigned short* __restrict__ fsb,
                                                 const unsigned short* __restrict__ ftb,
                                                 const float* __restrict__ inv_norm,
                                                 float* __restrict__ psum,
                                                 float2* __restrict__ pmax) {
  __shared__ __align__(16) char smem[29696];   // 3x8KB ring + 4KB psb + 1KB sInv
  float* psb  = (float*)(smem + 24576);        // [4 waves][256 n]
  float* sInv = (float*)(smem + 28672);        // [256]

  const int t = threadIdx.x;
  const int w = t >> 6, lane = t & 63;
  const int l15 = lane & 15, g = lane >> 4;
  const int bid = blockIdx.x;
  const int q = bid & 31, h = (bid >> 5) & 15, b = bid >> 9;
  const int m0 = q * 128 + w * 32;

  // staging: 8KB tile = 32 n-rows x 256B K; 2 segs/thread, involution swizzle
  const int r0 = t >> 4, cp0 = t & 15;
  const int src0 = r0 * 256 + ((cp0 ^ (r0 & 15)) << 4);               // rows 0..15
  const int src1 = (16 + r0) * 256 + ((cp0 ^ ((16 + r0) & 15)) << 4); // rows 16..31
  const int lds0 = w * 1024, lds1 = 4096 + w * 1024;   // wave-uniform bases

  // A fragments: ft rows m0..m0+31 (pre-scaled), straight from global, once
  const unsigned short* Ab = ftb + ((size_t)b * NN + m0) * DD;
  bf16x8 af[4][2];
#pragma unroll
  for (int kk = 0; kk < 4; kk++)
#pragma unroll
    for (int mf = 0; mf < 2; mf++)
      af[kk][mf] = *(const bf16x8*)(Ab + (mf * 16 + l15) * DD + kk * 32 + g * 8);

  // inv_norm slice -> LDS table (read in-loop via ds_read: lgkm domain only)
  sInv[t] = inv_norm[(size_t)b * NN + h * 256 + t];

  const char* gB0 = (const char*)(fsb + ((size_t)b * NN + h * 256) * DD);

  // drain ALL vmem (af loads) + publish sInv BEFORE any prefetch is in flight
  __syncthreads();

  char* b0 = smem;            // compute buffer (tile it)
  char* b1 = smem + 8192;     // tile it+1
  char* b2 = smem + 16384;    // tile it+2 (staging target)

  // prologue: stage tiles 0 and 1 -> 4 loads outstanding
  gload16(gB0 + src0, b0 + lds0);
  gload16(gB0 + src1, b0 + lds1);
  gload16(gB0 + 8192 + src0, b1 + lds0);
  gload16(gB0 + 8192 + src1, b1 + lds1);

  float bkey[2][4];
#pragma unroll
  for (int mf = 0; mf < 2; mf++)
#pragma unroll
    for (int j = 0; j < 4; j++) bkey[mf][j] = 0.0f;

#pragma unroll 1
  for (int it = 0; it < NIT - 1; ++it) {
    // tile it's 2 loads retired; tile it+1's 2 stay in flight
    asm volatile("s_waitcnt vmcnt(2)" ::: "memory");
    __builtin_amdgcn_s_barrier();   // all waves: tile it ready, ring slot free
    if (it < NIT - 2) {             // stage tile it+2 into b2
      const char* gBn = gB0 + (it + 2) * 8192;
      gload16(gBn + src0, b2 + lds0);
      gload16(gBn + src1, b2 + lds1);
    }
    // per-tile n-scales from LDS
    float svn[2];
    svn[0] = sInv[it * 32 + l15];
    svn[1] = sInv[it * 32 + 16 + l15];

    // MFMA: 32 m x 32 n, K=128
    f32x4 acc[2][2] = {};
#pragma unroll
    for (int kk = 0; kk < 4; kk++) {
      bf16x8 bf[2];
#pragma unroll
      for (int fj = 0; fj < 2; fj++)
        bf[fj] = *(const bf16x8*)(b0 + (fj * 16 + l15) * 256 + (((kk * 4 + g) ^ l15) << 4));
#pragma unroll
      for (int mf = 0; mf < 2; mf++)
#pragma unroll
        for (int fj = 0; fj < 2; fj++)
          mfma_16x16x32_bf16(acc[mf][fj], af[kk][mf], bf[fj]);
    }
    // exp col-sums over this wave's 32 m (acc = dot*0.1*log2e -> 2^acc)
#pragma unroll
    for (int fj = 0; fj < 2; fj++) {
      float e0 = vexp2(acc[0][fj][0]), e1 = vexp2(acc[0][fj][1]);
      float e2 = vexp2(acc[0][fj][2]), e3 = vexp2(acc[0][fj][3]);
      float e4 = vexp2(acc[1][fj][0]), e5 = vexp2(acc[1][fj][1]);
      float e6 = vexp2(acc[1][fj][2]), e7 = vexp2(acc[1][fj][3]);
      float s = ((e0 + e1) + (e2 + e3)) + ((e4 + e5) + (e6 + e7));
      s += __shfl_xor(s, 16);
      s += __shfl_xor(s, 32);
      if (g == 0) psb[w * 256 + it * 32 + fj * 16 + l15] = s;
    }
    // packed-key running argmax over n (fma, and_or, max per elem)
    const unsigned codebase = (unsigned)((7 - it) << 1);
#pragma unroll
    for (int fj = 0; fj < 2; fj++) {
      const unsigned code = codebase | (unsigned)(1 - fj);   // bigger = earlier n
#pragma unroll
      for (int mf = 0; mf < 2; mf++)
#pragma unroll
        for (int j = 0; j < 4; j++) {
          float v = fmaf(acc[mf][fj][j], svn[fj], 4.0f);     // positive -> uint order
          unsigned kb = (__float_as_uint(v) & 0xFFFFFFF0u) | code;
          bkey[mf][j] = fmaxf(bkey[mf][j], __uint_as_float(kb));
        }
    }
    char* tmp = b0; b0 = b1; b1 = b2; b2 = tmp;   // rotate ring
  }

  // epilogue iteration (it = NIT-1): only its own 2 loads outstanding
  {
    const int it = NIT - 1;
    asm volatile("s_waitcnt vmcnt(0)" ::: "memory");
    __builtin_amdgcn_s_barrier();
    float svn[2];
    svn[0] = sInv[it * 32 + l15];
    svn[1] = sInv[it * 32 + 16 + l15];
    f32x4 acc[2][2] = {};
#pragma unroll
    for (int kk = 0; kk < 4; kk++) {
      bf16x8 bf[2];
#pragma unroll
      for (int fj = 0; fj < 2; fj++)
        bf[fj] = *(const bf16x8*)(b0 + (fj * 16 + l15) * 256 + (((kk * 4 + g) ^ l15) << 4));
#pragma unroll
      for (int mf = 0; mf < 2; mf++)
#pragma unroll
        for (int fj = 0; fj < 2; fj++)
          mfma_16x16x32_bf16(acc[mf][fj], af[kk][mf], bf[fj]);
    }
#pragma unroll
    for (int fj = 0; fj < 2; fj++) {
      float e0 = vexp2(acc[0][fj][0]), e1 = vexp2(acc[0][fj][1]);
      float e2 = vexp2(acc[0][fj][2]), e3 = vexp2(acc[0][fj][3]);
      float e4 = vexp2(acc[1][fj][0]), e5 = vexp2(acc[1][fj][1]);
      float e6 = vexp2(acc[1][fj][2]), e7 = vexp2(acc[1][fj][3]);
      float s = ((e0 + e1) + (e2 + e3)) + ((e4 + e5) + (e6 + e7));
      s += __shfl_xor(s, 16);
      s += __shfl_xor(s, 32);
      if (g == 0) psb[w * 256 + it * 32 + fj * 16 + l15] = s;
    }
    const unsigned codebase = 0u;
#pragma unroll
    for (int fj = 0; fj < 2; fj++) {
      const unsigned code = codebase | (unsigned)(1 - fj);
#pragma unroll
      for (int mf = 0; mf < 2; mf++)
#pragma unroll
        for (int j = 0; j < 4; j++) {
          float v = fmaf(acc[mf][fj][j], svn[fj], 4.0f);
          unsigned kb = (__float_as_uint(v) & 0xFFFFFFF0u) | code;
          bkey[mf][j] = fmaxf(bkey[mf][j], __uint_as_float(kb));
        }
    }
  }
  __syncthreads();   // psb complete block-wide (full drain: loop is done)

  // psum write-out: combine 4 waves, coalesced (layout psum[b][q][n])
  {
    float s4 = (psb[t] + psb[256 + t]) + (psb[512 + t] + psb[768 + t]);
    psum[((size_t)(b * QG + q)) * NN + h * 256 + t] = s4;
  }

  // pmax finalize: exact cross-l15 argmax, once
#pragma unroll
  for (int mf = 0; mf < 2; mf++)
#pragma unroll
    for (int j = 0; j < 4; j++) {
      unsigned bits = __float_as_uint(bkey[mf][j]);
      unsigned code = bits & 15u;
      int itw = 7 - (int)(code >> 1);
      int fjw = 1 - (int)(code & 1u);
      int n = h * 256 + itw * 32 + fjw * 16 + l15;
      float vq = __uint_as_float(bits & 0xFFFFFFF0u);
#pragma unroll
      for (int off = 1; off <= 8; off <<= 1) {
        float ov = __shfl_xor(vq, off);
        int   on = __shfl_xor(n, off);
        if (ov > vq || (ov == vq && on < n)) { vq = ov; n = on; }
      }
      if (l15 == 0) {
        int m = m0 + mf * 16 + g * 4 + j;
        float2 pr; pr.x = vq; pr.y = __int_as_float(n);
        pmax[((size_t)b * NN + m) * HS + h] = pr;
      }
    }
}

// ---- kernel 3: per-row finish: argmax over 16 slices, sum 32 psum, pos dot -
__global__ __launch_bounds__(256) void k_post(const float* __restrict__ fs,
                                              const float* __restrict__ ft,
                                              const float* __restrict__ psum,
                                              const float2* __restrict__ pmax,
                                              float* __restrict__ blockpart) {
  __shared__ float part[4];
  int w = threadIdx.x >> 6, lane = threadIdx.x & 63;
  int row = blockIdx.x * 4 + w;          // flat b*N + p
  int b = row >> 12, pn = row & (NN - 1);
  // argmax over the 16 h-slices
  float v = -INFINITY; int i = 0x7fffffff;
  if (lane < HS) {
    float2 pm = pmax[(size_t)row * HS + lane];
    v = pm.x; i = __float_as_int(pm.y);
  }
#pragma unroll
  for (int off = 1; off <= 8; off <<= 1) {
    float ov = __shfl_xor(v, off);
    int   oi = __shfl_xor(i, off);
    if (ov > v || (ov == v && oi < i)) { v = ov; i = oi; }
  }
  int j = __shfl(i, 0);
  // sum the 32 q-partials of all_exp
  float tot = (lane < QG) ? psum[((size_t)(b * QG + lane)) * NN + pn] : 0.0f;
#pragma unroll
  for (int off = 1; off <= 16; off <<= 1) tot += __shfl_xor(tot, off);
  // fp32 dot of fs[row] with ft[b, j]
  float2 a = ((const float2*)(fs + (size_t)row * DD))[lane];
  float2 c = ((const float2*)(ft + ((size_t)b * NN + j) * DD))[lane];
  float s = a.x * c.x + a.y * c.y;
#pragma unroll
  for (int off = 32; off > 0; off >>= 1) s += __shfl_xor(s, off);
  if (lane == 0) {
    float term = logf(tot) - s * 0.1f;
    part[w] = fminf(term, 92.103403719761827f);   // ratio clip at 1e-40
  }
  __syncthreads();
  if (threadIdx.x == 0)
    blockpart[blockIdx.x] = part[0] + part[1] + part[2] + part[3];
}

// ---- kernel 4: final deterministic reduction ------------------------------
__global__ __launch_bounds__(256) void k_final(const float* __restrict__ blockpart,
                                               float* __restrict__ out) {
  __shared__ float red[256];
  float s = 0.0f;
  for (int i = threadIdx.x; i < (BB * NN) / 4; i += 256) s += blockpart[i];
  red[threadIdx.x] = s;
  __syncthreads();
  for (int st = 128; st > 0; st >>= 1) {
    if (threadIdx.x < st) red[threadIdx.x] += red[threadIdx.x + st];
    __syncthreads();
  }
  if (threadIdx.x == 0) out[0] = red[0] * (1.0f / (BB * NN));
}

extern "C" void kernel_launch(void* const* d_in, const int* in_sizes, int n_in,
                              void* d_out, int out_size, void* d_ws, size_t ws_size,
                              hipStream_t stream) {
  const float* fs = (const float*)d_in[0];
  const float* ft = (const float*)d_in[1];
  float* out = (float*)d_out;

  const size_t NE = (size_t)BB * NN * DD;
  unsigned short* fsb = (unsigned short*)d_ws;                   // 4MB
  unsigned short* ftb = fsb + NE;                                // 4MB
  float*  inv_norm = (float*)(ftb + NE);                         // 64KB
  float*  psum     = inv_norm + (size_t)BB * NN;                 // B*32*N f32 (2MB)
  float2* pmax     = (float2*)(psum + (size_t)BB * QG * NN);     // B*N*16 f32x2 (2MB)
  float*  blockpart = (float*)(pmax + (size_t)BB * NN * HS);     // B*N/4 f32

  k_prep<<<(int)(NE / 4 / 256), 256, 0, stream>>>(fs, ft, fsb, ftb, inv_norm);
  // k_main: b(4) x h(16) x q(32) = 2048 blocks
  k_main<<<BB * HS * QG, 256, 0, stream>>>(fsb, ftb, inv_norm, psum, pmax);
  k_post<<<(BB * NN) / 4, 256, 0, stream>>>(fs, ft, psum, pmax, blockpart);
  k_final<<<1, 256, 0, stream>>>(blockpart, out);
}